// Round 1
// baseline (2114.166 us; speedup 1.0000x reference)
//
#include <hip/hip_runtime.h>
#include <hip/hip_bf16.h>
#include <math.h>

typedef __attribute__((__ext_vector_type__(8))) __bf16 bf16x8;
typedef __attribute__((__ext_vector_type__(4))) float f32x4;

#define DIMQ 1024
#define SEQ 2048
#define NTOK 4096
#define HEADS 16
#define HD 64
#define MLPD 4096
#define DEPTH 6

__device__ __forceinline__ void gl_lds16(const __hip_bfloat16* g, __hip_bfloat16* l) {
  __builtin_amdgcn_global_load_lds((const __attribute__((address_space(1))) void*)(g),
                                   (__attribute__((address_space(3))) void*)(l), 16, 0, 0);
}

// ---------------- LayerNorm: one block per row (1024 cols) ----------------
__global__ __launch_bounds__(256) void ln_kernel(const float* __restrict__ h,
                                                 const float* __restrict__ g,
                                                 const float* __restrict__ bta,
                                                 __hip_bfloat16* __restrict__ y) {
  int row = blockIdx.x;
  int t = threadIdx.x;
  const float4* src = (const float4*)(h + (size_t)row * DIMQ);
  float4 xv = src[t];
  float s = xv.x + xv.y + xv.z + xv.w;
  float ss = xv.x * xv.x + xv.y * xv.y + xv.z * xv.z + xv.w * xv.w;
#pragma unroll
  for (int off = 32; off > 0; off >>= 1) {
    s += __shfl_xor(s, off);
    ss += __shfl_xor(ss, off);
  }
  __shared__ float red[8];
  int wid = t >> 6;
  if ((t & 63) == 0) { red[wid] = s; red[4 + wid] = ss; }
  __syncthreads();
  s = red[0] + red[1] + red[2] + red[3];
  ss = red[4] + red[5] + red[6] + red[7];
  float mean = s * (1.0f / DIMQ);
  float var = ss * (1.0f / DIMQ) - mean * mean;
  float rstd = rsqrtf(var + 1e-5f);
  float4 gv = ((const float4*)g)[t];
  float4 bv = ((const float4*)bta)[t];
  __hip_bfloat16* dst = y + (size_t)row * DIMQ + t * 4;
  dst[0] = __float2bfloat16((xv.x - mean) * rstd * gv.x + bv.x);
  dst[1] = __float2bfloat16((xv.y - mean) * rstd * gv.y + bv.y);
  dst[2] = __float2bfloat16((xv.z - mean) * rstd * gv.z + bv.z);
  dst[3] = __float2bfloat16((xv.w - mean) * rstd * gv.w + bv.w);
}

// ------------- Weight transpose+cast: in fp32 [K][N] -> out bf16 [N][K] -------------
__global__ __launch_bounds__(256) void transpose_cast(const float* __restrict__ in,
                                                      __hip_bfloat16* __restrict__ out,
                                                      int K, int N) {
  __shared__ float t[32][33];
  int n0 = blockIdx.x * 32, k0 = blockIdx.y * 32;
  int tx = threadIdx.x, ty = threadIdx.y;
#pragma unroll
  for (int i = 0; i < 32; i += 8)
    t[ty + i][tx] = in[(size_t)(k0 + ty + i) * N + n0 + tx];
  __syncthreads();
#pragma unroll
  for (int i = 0; i < 32; i += 8)
    out[(size_t)(n0 + ty + i) * K + k0 + tx] = __float2bfloat16(t[tx][ty + i]);
}

// ------------- V transpose: qkvb region2 [bh][n][d] -> vT [bh][d][n] -------------
__global__ __launch_bounds__(256) void vtrans(const __hip_bfloat16* __restrict__ qkvb,
                                              __hip_bfloat16* __restrict__ vT) {
  __shared__ __hip_bfloat16 t[32][33];
  int n0 = blockIdx.x * 32, d0 = blockIdx.y * 32, bh = blockIdx.z;
  int tx = threadIdx.x, ty = threadIdx.y;
#pragma unroll
  for (int i = 0; i < 32; i += 8)
    t[ty + i][tx] = qkvb[((size_t)(64 + bh) * SEQ + n0 + ty + i) * HD + d0 + tx];
  __syncthreads();
#pragma unroll
  for (int i = 0; i < 32; i += 8)
    vT[((size_t)bh * HD + d0 + ty + i) * SEQ + n0 + tx] = t[tx][ty + i];
}

// ---------------- GEMM 128x128, BK=64, XOR-swizzled LDS, XCD-swizzled grid ----------------
// EPI 1: bf16 gelu(x+bias). EPI 3: bf16 scatter to qkv [which][bh][n][d].
template <int EPI>
__global__ __launch_bounds__(256)
void gemm128(const __hip_bfloat16* __restrict__ A, const __hip_bfloat16* __restrict__ BT,
             const float* __restrict__ bias, void* __restrict__ outp,
             int M, int N, int K, int gpx) {
  __shared__ __hip_bfloat16 As[128][64];
  __shared__ __hip_bfloat16 Bs[128][64];
  int bid = blockIdx.x;
  int xcd = bid & 7, jb = bid >> 3;
  int nt = xcd * gpx + (jb % gpx), mt = jb / gpx;
  int m0 = mt * 128, n0 = nt * 128;
  int tid = threadIdx.x;
  int lane = tid & 63, wid = tid >> 6;
  int l16 = lane & 15, quad = lane >> 4;
  int wm = (wid >> 1) * 64, wn = (wid & 1) * 64;
  int srsub = lane >> 3;
  int sg = (lane & 7) ^ srsub;
  f32x4 acc[4][4] = {};
  for (int kt = 0; kt < K; kt += 64) {
    __syncthreads();
#pragma unroll
    for (int s = 0; s < 4; ++s) {
      int r0 = (wid * 4 + s) * 8;
      gl_lds16(A + (size_t)(m0 + r0 + srsub) * K + kt + sg * 8, &As[r0][0]);
      gl_lds16(BT + (size_t)(n0 + r0 + srsub) * K + kt + sg * 8, &Bs[r0][0]);
    }
    __syncthreads();
#pragma unroll
    for (int ks = 0; ks < 2; ++ks) {
      bf16x8 af[4], bfr[4];
      int p = (ks * 4 + quad) ^ (l16 & 7);
#pragma unroll
      for (int i = 0; i < 4; ++i) af[i] = *(const bf16x8*)&As[wm + i * 16 + l16][p * 8];
#pragma unroll
      for (int j = 0; j < 4; ++j) bfr[j] = *(const bf16x8*)&Bs[wn + j * 16 + l16][p * 8];
#pragma unroll
      for (int i = 0; i < 4; ++i)
#pragma unroll
        for (int j = 0; j < 4; ++j)
          acc[i][j] = __builtin_amdgcn_mfma_f32_16x16x32_bf16(af[i], bfr[j], acc[i][j], 0, 0, 0);
    }
  }
#pragma unroll
  for (int j = 0; j < 4; ++j) {
    int col = n0 + wn + j * 16 + l16;
    float bv = (EPI == 3) ? 0.0f : bias[col];
#pragma unroll
    for (int i = 0; i < 4; ++i) {
#pragma unroll
      for (int r = 0; r < 4; ++r) {
        int row = m0 + wm + i * 16 + quad * 4 + r;
        float v = acc[i][j][r];
        if (EPI == 1) {
          v += bv;
          v = 0.5f * v * (1.0f + erff(v * 0.70710678118654752f));
          ((__hip_bfloat16*)outp)[(size_t)row * N + col] = __float2bfloat16(v);
        } else {  // EPI 3: qkv scatter [which][b,h][n][d]
          int which = col >> 10;
          int head = (col >> 6) & 15;
          int d = col & 63;
          size_t dst = (((size_t)which * 32 + (row >> 11) * 16 + head) * SEQ + (row & 2047)) * HD + d;
          ((__hip_bfloat16*)outp)[dst] = __float2bfloat16(v);
        }
      }
    }
  }
}

// ---------------- GEMM 128x64, BK=64: fp32 residual h += acc + bias (no atomics) ----------
__global__ __launch_bounds__(256, 5)
void gemm64_res(const __hip_bfloat16* __restrict__ A, const __hip_bfloat16* __restrict__ BT,
                const float* __restrict__ bias, float* __restrict__ h,
                int M, int N, int K, int gpx) {
  __shared__ __hip_bfloat16 As[128][64];  // 16 KB
  __shared__ __hip_bfloat16 Bs[64][64];   // 8 KB
  int bid = blockIdx.x;
  int xcd = bid & 7, jb = bid >> 3;
  int nt = xcd * gpx + (jb % gpx), mt = jb / gpx;
  int m0 = mt * 128, n0 = nt * 64;
  int tid = threadIdx.x;
  int lane = tid & 63, wid = tid >> 6;
  int l16 = lane & 15, quad = lane >> 4;
  int wm = (wid >> 1) * 64, wn = (wid & 1) * 32;
  int srsub = lane >> 3;
  int sg = (lane & 7) ^ srsub;
  f32x4 acc[4][2] = {};
  for (int kt = 0; kt < K; kt += 64) {
    __syncthreads();
#pragma unroll
    for (int s = 0; s < 4; ++s) {
      int r0 = (wid * 4 + s) * 8;
      gl_lds16(A + (size_t)(m0 + r0 + srsub) * K + kt + sg * 8, &As[r0][0]);
    }
#pragma unroll
    for (int s = 0; s < 2; ++s) {
      int r0 = (wid * 2 + s) * 8;
      gl_lds16(BT + (size_t)(n0 + r0 + srsub) * K + kt + sg * 8, &Bs[r0][0]);
    }
    __syncthreads();
#pragma unroll
    for (int ks = 0; ks < 2; ++ks) {
      bf16x8 af[4], bfr[2];
      int p = (ks * 4 + quad) ^ (l16 & 7);
#pragma unroll
      for (int i = 0; i < 4; ++i) af[i] = *(const bf16x8*)&As[wm + i * 16 + l16][p * 8];
#pragma unroll
      for (int j = 0; j < 2; ++j) bfr[j] = *(const bf16x8*)&Bs[wn + j * 16 + l16][p * 8];
#pragma unroll
      for (int i = 0; i < 4; ++i)
#pragma unroll
        for (int j = 0; j < 2; ++j)
          acc[i][j] = __builtin_amdgcn_mfma_f32_16x16x32_bf16(af[i], bfr[j], acc[i][j], 0, 0, 0);
    }
  }
#pragma unroll
  for (int j = 0; j < 2; ++j) {
    int col = n0 + wn + j * 16 + l16;
    float bv = bias[col];
#pragma unroll
    for (int i = 0; i < 4; ++i) {
#pragma unroll
      for (int r = 0; r < 4; ++r) {
        int row = m0 + wm + i * 16 + quad * 4 + r;
        size_t idx = (size_t)row * N + col;
        h[idx] = h[idx] + acc[i][j][r] + bv;
      }
    }
  }
}

// ---------------- Flash attention: double-buffered K/V LDS, counted vmcnt pipeline ----------
// Per tile: wait vmcnt(4) (current tile's 4 loads done, next tile's 4 stay in flight),
// raw s_barrier, compute (QK^T -> no-max softmax -> PV), barrier, stage tile+2 into
// the just-freed buffer. No vmcnt(0) drain anywhere in the main loop (T3/T4).
__global__ __launch_bounds__(256)
void attn_kernel(const __hip_bfloat16* __restrict__ qkvb, const __hip_bfloat16* __restrict__ vT,
                 __hip_bfloat16* __restrict__ o) {
  __shared__ __hip_bfloat16 Ks[2][64][64];
  __shared__ __hip_bfloat16 Vs[2][64][64];
  __shared__ __hip_bfloat16 Ps[4][16][68];
  int bh = blockIdx.y;
  int b = bh >> 4;
  int tid = threadIdx.x;
  int wid = tid >> 6, lane = tid & 63;
  int l16 = lane & 15, quad = lane >> 4;
  int qrow = blockIdx.x * 64 + wid * 16 + l16;
  const __hip_bfloat16* qp = qkvb + ((size_t)bh * SEQ + qrow) * HD;
  bf16x8 qf0 = *(const bf16x8*)(qp + quad * 8);
  bf16x8 qf1 = *(const bf16x8*)(qp + 32 + quad * 8);
  f32x4 oacc[4] = {};
  float lsum[4] = {0.0f, 0.0f, 0.0f, 0.0f};
  int srsub = lane >> 3;
  int sg = (lane & 7) ^ srsub;
  const __hip_bfloat16* kbase = qkvb + (size_t)(32 + bh) * SEQ * HD;
  const __hip_bfloat16* vbase = vT + (size_t)bh * HD * SEQ;
  const float c1 = 0.045084220027780106f;  // 1024^-0.5 * log2(e)

  int r0 = wid * 16, r1 = wid * 16 + 8;
  // stage tile starting at key-row kb into buffer bi: 4 gl_lds16 per thread
#define STAGE_KV(bi, kb)                                                          \
  do {                                                                            \
    gl_lds16(kbase + (size_t)((kb) + r0 + srsub) * HD + sg * 8, &Ks[bi][r0][0]);  \
    gl_lds16(kbase + (size_t)((kb) + r1 + srsub) * HD + sg * 8, &Ks[bi][r1][0]);  \
    gl_lds16(vbase + (size_t)(r0 + srsub) * SEQ + (kb) + sg * 8, &Vs[bi][r0][0]); \
    gl_lds16(vbase + (size_t)(r1 + srsub) * SEQ + (kb) + sg * 8, &Vs[bi][r1][0]); \
  } while (0)

  STAGE_KV(0, 0);
  STAGE_KV(1, 64);

  for (int kb = 0; kb < SEQ; kb += 64) {
    int cur = (kb >> 6) & 1;
    // current tile's 4 loads are the oldest 4 outstanding; leave next tile's 4 in flight
    asm volatile("s_waitcnt vmcnt(4)" ::: "memory");
    asm volatile("s_barrier" ::: "memory");
    f32x4 sc[4];
    int p0 = quad ^ (l16 & 7);
    int p1 = (4 + quad) ^ (l16 & 7);
    __builtin_amdgcn_s_setprio(1);
#pragma unroll
    for (int c = 0; c < 4; ++c) {
      int r = c * 16 + l16;
      bf16x8 k0 = *(const bf16x8*)&Ks[cur][r][p0 * 8];
      bf16x8 k1 = *(const bf16x8*)&Ks[cur][r][p1 * 8];
      f32x4 z = {};
      z = __builtin_amdgcn_mfma_f32_16x16x32_bf16(qf0, k0, z, 0, 0, 0);
      z = __builtin_amdgcn_mfma_f32_16x16x32_bf16(qf1, k1, z, 0, 0, 0);
      sc[c] = z;
    }
    __builtin_amdgcn_s_setprio(0);
#pragma unroll
    for (int r = 0; r < 4; ++r) {
      float psum = 0.0f;
#pragma unroll
      for (int c = 0; c < 4; ++c) {
        float p = exp2f(sc[c][r] * c1);
        psum += p;
        Ps[wid][quad * 4 + r][c * 16 + l16] = __float2bfloat16(p);
      }
      lsum[r] += psum;
    }
    asm volatile("s_waitcnt lgkmcnt(0)" ::: "memory");
    bf16x8 pf0 = *(const bf16x8*)&Ps[wid][l16][quad * 8];
    bf16x8 pf1 = *(const bf16x8*)&Ps[wid][l16][32 + quad * 8];
    __builtin_amdgcn_s_setprio(1);
#pragma unroll
    for (int f = 0; f < 4; ++f) {
      int r = f * 16 + l16;
      bf16x8 v0 = *(const bf16x8*)&Vs[cur][r][p0 * 8];
      bf16x8 v1 = *(const bf16x8*)&Vs[cur][r][p1 * 8];
      oacc[f] = __builtin_amdgcn_mfma_f32_16x16x32_bf16(pf0, v0, oacc[f], 0, 0, 0);
      oacc[f] = __builtin_amdgcn_mfma_f32_16x16x32_bf16(pf1, v1, oacc[f], 0, 0, 0);
    }
    __builtin_amdgcn_s_setprio(0);
    asm volatile("s_barrier" ::: "memory");
    // stage tile kb+128 into the buffer just freed (wrap keeps vmcnt bookkeeping uniform;
    // the tail's wrapped reloads are never read)
    int nk = kb + 128;
    if (nk >= SEQ) nk = 0;
    STAGE_KV(cur, nk);
  }
#undef STAGE_KV

#pragma unroll
  for (int r = 0; r < 4; ++r) {
#pragma unroll
    for (int off = 1; off < 16; off <<= 1) lsum[r] += __shfl_xor(lsum[r], off);
  }
  int h = bh & 15;
  int orow = b * SEQ + blockIdx.x * 64 + wid * 16 + quad * 4;
#pragma unroll
  for (int r = 0; r < 4; ++r) {
    float inv = 1.0f / lsum[r];
#pragma unroll
    for (int f = 0; f < 4; ++f) {
      o[(size_t)(orow + r) * DIMQ + h * HD + f * 16 + l16] = __float2bfloat16(oacc[f][r] * inv);
    }
  }
}

// ---------------- Launcher ----------------
extern "C" void kernel_launch(void* const* d_in, const int* in_sizes, int n_in,
                              void* d_out, int out_size, void* d_ws, size_t ws_size,
                              hipStream_t stream) {
  const float* x = (const float*)d_in[0];
  const float* Wqkv = (const float*)d_in[1];
  const float* Wout = (const float*)d_in[2];
  const float* bout = (const float*)d_in[3];
  const float* ln1g = (const float*)d_in[4];
  const float* ln1b = (const float*)d_in[5];
  const float* ln2g = (const float*)d_in[6];
  const float* ln2b = (const float*)d_in[7];
  const float* W1 = (const float*)d_in[8];
  const float* b1 = (const float*)d_in[9];
  const float* W2 = (const float*)d_in[10];
  const float* b2 = (const float*)d_in[11];
  float* h = (float*)d_out;

  char* ws = (char*)d_ws;
  __hip_bfloat16* wqkvT = (__hip_bfloat16*)ws; ws += (size_t)3072 * 1024 * 2;
  __hip_bfloat16* woutT = (__hip_bfloat16*)ws; ws += (size_t)1024 * 1024 * 2;
  __hip_bfloat16* w1T = (__hip_bfloat16*)ws;   ws += (size_t)4096 * 1024 * 2;
  __hip_bfloat16* w2T = (__hip_bfloat16*)ws;   ws += (size_t)1024 * 4096 * 2;
  __hip_bfloat16* ybuf = (__hip_bfloat16*)ws;  ws += (size_t)NTOK * 1024 * 2;
  __hip_bfloat16* qkvb = (__hip_bfloat16*)ws;  ws += (size_t)NTOK * 3072 * 2;
  __hip_bfloat16* vTb = (__hip_bfloat16*)ws;   ws += (size_t)32 * HD * SEQ * 2;
  __hip_bfloat16* obuf = (__hip_bfloat16*)ws;  ws += (size_t)NTOK * 1024 * 2;
  __hip_bfloat16* actb = (__hip_bfloat16*)ws;  ws += (size_t)NTOK * MLPD * 2;

  hipMemcpyAsync(h, x, (size_t)out_size * sizeof(float), hipMemcpyDeviceToDevice, stream);

  dim3 tb(32, 8);
  for (int l = 0; l < DEPTH; ++l) {
    transpose_cast<<<dim3(3072 / 32, 1024 / 32), tb, 0, stream>>>(
        Wqkv + (size_t)l * 1024 * 3072, wqkvT, 1024, 3072);
    transpose_cast<<<dim3(1024 / 32, 1024 / 32), tb, 0, stream>>>(
        Wout + (size_t)l * 1024 * 1024, woutT, 1024, 1024);
    transpose_cast<<<dim3(4096 / 32, 1024 / 32), tb, 0, stream>>>(
        W1 + (size_t)l * 1024 * 4096, w1T, 1024, 4096);
    transpose_cast<<<dim3(1024 / 32, 4096 / 32), tb, 0, stream>>>(
        W2 + (size_t)l * 4096 * 1024, w2T, 4096, 1024);

    ln_kernel<<<NTOK, 256, 0, stream>>>(h, ln1g + l * 1024, ln1b + l * 1024, ybuf);
    // QKV: N=3072 -> 24 n-tiles, gpx=3; 768 blocks
    gemm128<3><<<768, 256, 0, stream>>>(ybuf, wqkvT, nullptr, qkvb, NTOK, 3072, 1024, 3);
    vtrans<<<dim3(SEQ / 32, 2, 32), tb, 0, stream>>>(qkvb, vTb);
    attn_kernel<<<dim3(SEQ / 64, 32), 256, 0, stream>>>(qkvb, vTb, obuf);
    // Oproj: N=1024 -> 16 n-tiles(64) , gpx=2; 512 blocks, residual into h
    gemm64_res<<<512, 256, 0, stream>>>(obuf, woutT, bout + l * 1024, h, NTOK, 1024, 1024, 2);

    ln_kernel<<<NTOK, 256, 0, stream>>>(h, ln2g + l * 1024, ln2b + l * 1024, ybuf);
    // MLP1: N=4096 -> 32 n-tiles, gpx=4; 1024 blocks
    gemm128<1><<<1024, 256, 0, stream>>>(ybuf, w1T, b1 + l * 4096, actb, NTOK, 4096, 1024, 4);
    // MLP2: N=1024 -> 16 n-tiles(64), gpx=2; 512 blocks, K=4096, residual into h
    gemm64_res<<<512, 256, 0, stream>>>(actb, w2T, b2 + l * 1024, h, NTOK, 1024, 4096, 2);
  }
}

// Round 2
// 2009.868 us; speedup vs baseline: 1.0519x; 1.0519x over previous
//
#include <hip/hip_runtime.h>
#include <hip/hip_bf16.h>
#include <math.h>

typedef __attribute__((__ext_vector_type__(8))) __bf16 bf16x8;
typedef __attribute__((__ext_vector_type__(4))) float f32x4;

#define DIMQ 1024
#define SEQ 2048
#define NTOK 4096
#define HEADS 16
#define HD 64
#define MLPD 4096
#define DEPTH 6

__device__ __forceinline__ void gl_lds16(const __hip_bfloat16* g, __hip_bfloat16* l) {
  __builtin_amdgcn_global_load_lds((const __attribute__((address_space(1))) void*)(g),
                                   (__attribute__((address_space(3))) void*)(l), 16, 0, 0);
}

// packed f32x2 -> bf16x2 (RNE) in one instruction
__device__ __forceinline__ unsigned cvtpk_bf16(float lo, float hi) {
  unsigned r;
  asm("v_cvt_pk_bf16_f32 %0, %1, %2" : "=v"(r) : "v"(lo), "v"(hi));
  return r;
}

// ---------------- LayerNorm: one block per row (1024 cols) ----------------
__global__ __launch_bounds__(256) void ln_kernel(const float* __restrict__ h,
                                                 const float* __restrict__ g,
                                                 const float* __restrict__ bta,
                                                 __hip_bfloat16* __restrict__ y) {
  int row = blockIdx.x;
  int t = threadIdx.x;
  const float4* src = (const float4*)(h + (size_t)row * DIMQ);
  float4 xv = src[t];
  float s = xv.x + xv.y + xv.z + xv.w;
  float ss = xv.x * xv.x + xv.y * xv.y + xv.z * xv.z + xv.w * xv.w;
#pragma unroll
  for (int off = 32; off > 0; off >>= 1) {
    s += __shfl_xor(s, off);
    ss += __shfl_xor(ss, off);
  }
  __shared__ float red[8];
  int wid = t >> 6;
  if ((t & 63) == 0) { red[wid] = s; red[4 + wid] = ss; }
  __syncthreads();
  s = red[0] + red[1] + red[2] + red[3];
  ss = red[4] + red[5] + red[6] + red[7];
  float mean = s * (1.0f / DIMQ);
  float var = ss * (1.0f / DIMQ) - mean * mean;
  float rstd = rsqrtf(var + 1e-5f);
  float4 gv = ((const float4*)g)[t];
  float4 bv = ((const float4*)bta)[t];
  __hip_bfloat16* dst = y + (size_t)row * DIMQ + t * 4;
  dst[0] = __float2bfloat16((xv.x - mean) * rstd * gv.x + bv.x);
  dst[1] = __float2bfloat16((xv.y - mean) * rstd * gv.y + bv.y);
  dst[2] = __float2bfloat16((xv.z - mean) * rstd * gv.z + bv.z);
  dst[3] = __float2bfloat16((xv.w - mean) * rstd * gv.w + bv.w);
}

// ------- Batched weight transpose+cast: 4 matrices, fp32 [K][N] -> bf16 [N][K] -------
// tiles: Wqkv 96x32=3072, Wout 32x32=1024, W1 128x32=4096, W2 32x128=4096 -> 12288
__global__ __launch_bounds__(256)
void transpose_cast4(const float* __restrict__ s0, const float* __restrict__ s1,
                     const float* __restrict__ s2, const float* __restrict__ s3,
                     __hip_bfloat16* __restrict__ d0, __hip_bfloat16* __restrict__ d1,
                     __hip_bfloat16* __restrict__ d2, __hip_bfloat16* __restrict__ d3) {
  __shared__ float t[32][33];
  int tb = blockIdx.x;
  const float* src;
  __hip_bfloat16* dst;
  int K, N;
  if (tb < 3072) { src = s0; dst = d0; K = 1024; N = 3072; }
  else if (tb < 4096) { tb -= 3072; src = s1; dst = d1; K = 1024; N = 1024; }
  else if (tb < 8192) { tb -= 4096; src = s2; dst = d2; K = 1024; N = 4096; }
  else { tb -= 8192; src = s3; dst = d3; K = 4096; N = 1024; }
  int ntx = N >> 5;
  int n0 = (tb % ntx) * 32, k0 = (tb / ntx) * 32;
  int tx = threadIdx.x, ty = threadIdx.y;
#pragma unroll
  for (int i = 0; i < 32; i += 8)
    t[ty + i][tx] = src[(size_t)(k0 + ty + i) * N + n0 + tx];
  __syncthreads();
#pragma unroll
  for (int i = 0; i < 32; i += 8)
    dst[(size_t)(n0 + ty + i) * K + k0 + tx] = __float2bfloat16(t[tx][ty + i]);
}

// ---------------- GEMM 128x128, BK=64, XOR-swizzled LDS, XCD-swizzled grid ----------------
// EPI 1: bf16 gelu(x+bias). EPI 3: bf16 scatter to qkv [which][bh][n][d] for Q/K;
//        V columns (which==2) go straight to vT [bh][d][n] (fused V-transpose).
template <int EPI>
__global__ __launch_bounds__(256)
void gemm128(const __hip_bfloat16* __restrict__ A, const __hip_bfloat16* __restrict__ BT,
             const float* __restrict__ bias, void* __restrict__ outp, void* __restrict__ outp2,
             int M, int N, int K, int gpx) {
  __shared__ __hip_bfloat16 As[128][64];
  __shared__ __hip_bfloat16 Bs[128][64];
  int bid = blockIdx.x;
  int xcd = bid & 7, jb = bid >> 3;
  int nt = xcd * gpx + (jb % gpx), mt = jb / gpx;
  int m0 = mt * 128, n0 = nt * 128;
  int tid = threadIdx.x;
  int lane = tid & 63, wid = tid >> 6;
  int l16 = lane & 15, quad = lane >> 4;
  int wm = (wid >> 1) * 64, wn = (wid & 1) * 64;
  int srsub = lane >> 3;
  int sg = (lane & 7) ^ srsub;
  f32x4 acc[4][4] = {};
  for (int kt = 0; kt < K; kt += 64) {
    __syncthreads();
#pragma unroll
    for (int s = 0; s < 4; ++s) {
      int r0 = (wid * 4 + s) * 8;
      gl_lds16(A + (size_t)(m0 + r0 + srsub) * K + kt + sg * 8, &As[r0][0]);
      gl_lds16(BT + (size_t)(n0 + r0 + srsub) * K + kt + sg * 8, &Bs[r0][0]);
    }
    __syncthreads();
#pragma unroll
    for (int ks = 0; ks < 2; ++ks) {
      bf16x8 af[4], bfr[4];
      int p = (ks * 4 + quad) ^ (l16 & 7);
#pragma unroll
      for (int i = 0; i < 4; ++i) af[i] = *(const bf16x8*)&As[wm + i * 16 + l16][p * 8];
#pragma unroll
      for (int j = 0; j < 4; ++j) bfr[j] = *(const bf16x8*)&Bs[wn + j * 16 + l16][p * 8];
#pragma unroll
      for (int i = 0; i < 4; ++i)
#pragma unroll
        for (int j = 0; j < 4; ++j)
          acc[i][j] = __builtin_amdgcn_mfma_f32_16x16x32_bf16(af[i], bfr[j], acc[i][j], 0, 0, 0);
    }
  }
#pragma unroll
  for (int j = 0; j < 4; ++j) {
    int col = n0 + wn + j * 16 + l16;
    if (EPI == 1) {
      float bv = bias[col];
#pragma unroll
      for (int i = 0; i < 4; ++i) {
#pragma unroll
        for (int r = 0; r < 4; ++r) {
          int row = m0 + wm + i * 16 + quad * 4 + r;
          float v = acc[i][j][r] + bv;
          v = 0.5f * v * (1.0f + erff(v * 0.70710678118654752f));
          ((__hip_bfloat16*)outp)[(size_t)row * N + col] = __float2bfloat16(v);
        }
      }
    } else {  // EPI 3
      int which = col >> 10;
      int head = (col >> 6) & 15;
      int d = col & 63;
      if (which < 2) {  // Q/K scatter to qkv [which][b,h][n][d]
#pragma unroll
        for (int i = 0; i < 4; ++i) {
#pragma unroll
          for (int r = 0; r < 4; ++r) {
            int row = m0 + wm + i * 16 + quad * 4 + r;
            size_t dst = (((size_t)which * 32 + (row >> 11) * 16 + head) * SEQ + (row & 2047)) * HD + d;
            ((__hip_bfloat16*)outp)[dst] = __float2bfloat16(acc[i][j][r]);
          }
        }
      } else {  // V: write vT [bh][d][n] directly, 4 consecutive n packed per store
        int bh2 = ((m0 >> 11) << 4) + head;  // block never straddles the b boundary
        unsigned short* vrow = (unsigned short*)outp2 + ((size_t)bh2 * HD + d) * SEQ;
        int nb = (m0 & 2047) + wm + quad * 4;
#pragma unroll
        for (int i = 0; i < 4; ++i) {
          uint2 pk;
          pk.x = cvtpk_bf16(acc[i][j][0], acc[i][j][1]);
          pk.y = cvtpk_bf16(acc[i][j][2], acc[i][j][3]);
          *(uint2*)(vrow + nb + i * 16) = pk;
        }
      }
    }
  }
}

// ---------------- GEMM 128x64, BK=64: fp32 residual h += acc + bias (no atomics) ----------
__global__ __launch_bounds__(256, 5)
void gemm64_res(const __hip_bfloat16* __restrict__ A, const __hip_bfloat16* __restrict__ BT,
                const float* __restrict__ bias, float* __restrict__ h,
                int M, int N, int K, int gpx) {
  __shared__ __hip_bfloat16 As[128][64];  // 16 KB
  __shared__ __hip_bfloat16 Bs[64][64];   // 8 KB
  int bid = blockIdx.x;
  int xcd = bid & 7, jb = bid >> 3;
  int nt = xcd * gpx + (jb % gpx), mt = jb / gpx;
  int m0 = mt * 128, n0 = nt * 64;
  int tid = threadIdx.x;
  int lane = tid & 63, wid = tid >> 6;
  int l16 = lane & 15, quad = lane >> 4;
  int wm = (wid >> 1) * 64, wn = (wid & 1) * 32;
  int srsub = lane >> 3;
  int sg = (lane & 7) ^ srsub;
  f32x4 acc[4][2] = {};
  for (int kt = 0; kt < K; kt += 64) {
    __syncthreads();
#pragma unroll
    for (int s = 0; s < 4; ++s) {
      int r0 = (wid * 4 + s) * 8;
      gl_lds16(A + (size_t)(m0 + r0 + srsub) * K + kt + sg * 8, &As[r0][0]);
    }
#pragma unroll
    for (int s = 0; s < 2; ++s) {
      int r0 = (wid * 2 + s) * 8;
      gl_lds16(BT + (size_t)(n0 + r0 + srsub) * K + kt + sg * 8, &Bs[r0][0]);
    }
    __syncthreads();
#pragma unroll
    for (int ks = 0; ks < 2; ++ks) {
      bf16x8 af[4], bfr[2];
      int p = (ks * 4 + quad) ^ (l16 & 7);
#pragma unroll
      for (int i = 0; i < 4; ++i) af[i] = *(const bf16x8*)&As[wm + i * 16 + l16][p * 8];
#pragma unroll
      for (int j = 0; j < 2; ++j) bfr[j] = *(const bf16x8*)&Bs[wn + j * 16 + l16][p * 8];
#pragma unroll
      for (int i = 0; i < 4; ++i)
#pragma unroll
        for (int j = 0; j < 2; ++j)
          acc[i][j] = __builtin_amdgcn_mfma_f32_16x16x32_bf16(af[i], bfr[j], acc[i][j], 0, 0, 0);
    }
  }
#pragma unroll
  for (int j = 0; j < 2; ++j) {
    int col = n0 + wn + j * 16 + l16;
    float bv = bias[col];
#pragma unroll
    for (int i = 0; i < 4; ++i) {
#pragma unroll
      for (int r = 0; r < 4; ++r) {
        int row = m0 + wm + i * 16 + quad * 4 + r;
        size_t idx = (size_t)row * N + col;
        h[idx] = h[idx] + acc[i][j][r] + bv;
      }
    }
  }
}

// ---------------- Flash attention: LDS-staged K/V tiles, no-max softmax ----------------
__global__ __launch_bounds__(256)
void attn_kernel(const __hip_bfloat16* __restrict__ qkvb, const __hip_bfloat16* __restrict__ vT,
                 __hip_bfloat16* __restrict__ o) {
  __shared__ __hip_bfloat16 Ks[64][64];
  __shared__ __hip_bfloat16 Vs[64][64];
  __shared__ __hip_bfloat16 Ps[4][16][68];
  int bh = blockIdx.y;
  int b = bh >> 4;
  int tid = threadIdx.x;
  int wid = tid >> 6, lane = tid & 63;
  int l16 = lane & 15, quad = lane >> 4;
  int qrow = blockIdx.x * 64 + wid * 16 + l16;
  const __hip_bfloat16* qp = qkvb + ((size_t)bh * SEQ + qrow) * HD;
  bf16x8 qf0 = *(const bf16x8*)(qp + quad * 8);
  bf16x8 qf1 = *(const bf16x8*)(qp + 32 + quad * 8);
  f32x4 oacc[4] = {};
  float lsum[4] = {0.0f, 0.0f, 0.0f, 0.0f};
  int srsub = lane >> 3;
  int sg = (lane & 7) ^ srsub;
  const __hip_bfloat16* kbase = qkvb + (size_t)(32 + bh) * SEQ * HD;
  const __hip_bfloat16* vbase = vT + (size_t)bh * HD * SEQ;
  const float c1 = 0.045084220027780106f;  // 1024^-0.5 * log2(e)
  for (int kb = 0; kb < SEQ; kb += 64) {
    __syncthreads();
    {
      int r0 = wid * 16, r1 = wid * 16 + 8;
      gl_lds16(kbase + (size_t)(kb + r0 + srsub) * HD + sg * 8, &Ks[r0][0]);
      gl_lds16(kbase + (size_t)(kb + r1 + srsub) * HD + sg * 8, &Ks[r1][0]);
      gl_lds16(vbase + (size_t)(r0 + srsub) * SEQ + kb + sg * 8, &Vs[r0][0]);
      gl_lds16(vbase + (size_t)(r1 + srsub) * SEQ + kb + sg * 8, &Vs[r1][0]);
    }
    __syncthreads();
    f32x4 sc[4];
    int p0 = quad ^ (l16 & 7);
    int p1 = (4 + quad) ^ (l16 & 7);
#pragma unroll
    for (int c = 0; c < 4; ++c) {
      int r = c * 16 + l16;
      bf16x8 k0 = *(const bf16x8*)&Ks[r][p0 * 8];
      bf16x8 k1 = *(const bf16x8*)&Ks[r][p1 * 8];
      f32x4 z = {};
      z = __builtin_amdgcn_mfma_f32_16x16x32_bf16(qf0, k0, z, 0, 0, 0);
      z = __builtin_amdgcn_mfma_f32_16x16x32_bf16(qf1, k1, z, 0, 0, 0);
      sc[c] = z;
    }
#pragma unroll
    for (int r = 0; r < 4; ++r) {
      float psum = 0.0f;
#pragma unroll
      for (int c = 0; c < 4; ++c) {
        float p = exp2f(sc[c][r] * c1);
        psum += p;
        Ps[wid][quad * 4 + r][c * 16 + l16] = __float2bfloat16(p);
      }
      lsum[r] += psum;
    }
    asm volatile("s_waitcnt lgkmcnt(0)" ::: "memory");
    bf16x8 pf0 = *(const bf16x8*)&Ps[wid][l16][quad * 8];
    bf16x8 pf1 = *(const bf16x8*)&Ps[wid][l16][32 + quad * 8];
#pragma unroll
    for (int f = 0; f < 4; ++f) {
      int r = f * 16 + l16;
      bf16x8 v0 = *(const bf16x8*)&Vs[r][p0 * 8];
      bf16x8 v1 = *(const bf16x8*)&Vs[r][p1 * 8];
      oacc[f] = __builtin_amdgcn_mfma_f32_16x16x32_bf16(pf0, v0, oacc[f], 0, 0, 0);
      oacc[f] = __builtin_amdgcn_mfma_f32_16x16x32_bf16(pf1, v1, oacc[f], 0, 0, 0);
    }
  }
#pragma unroll
  for (int r = 0; r < 4; ++r) {
#pragma unroll
    for (int off = 1; off < 16; off <<= 1) lsum[r] += __shfl_xor(lsum[r], off);
  }
  int h = bh & 15;
  int orow = b * SEQ + blockIdx.x * 64 + wid * 16 + quad * 4;
#pragma unroll
  for (int r = 0; r < 4; ++r) {
    float inv = 1.0f / lsum[r];
#pragma unroll
    for (int f = 0; f < 4; ++f) {
      o[(size_t)(orow + r) * DIMQ + h * HD + f * 16 + l16] = __float2bfloat16(oacc[f][r] * inv);
    }
  }
}

// ---------------- Launcher ----------------
extern "C" void kernel_launch(void* const* d_in, const int* in_sizes, int n_in,
                              void* d_out, int out_size, void* d_ws, size_t ws_size,
                              hipStream_t stream) {
  const float* x = (const float*)d_in[0];
  const float* Wqkv = (const float*)d_in[1];
  const float* Wout = (const float*)d_in[2];
  const float* bout = (const float*)d_in[3];
  const float* ln1g = (const float*)d_in[4];
  const float* ln1b = (const float*)d_in[5];
  const float* ln2g = (const float*)d_in[6];
  const float* ln2b = (const float*)d_in[7];
  const float* W1 = (const float*)d_in[8];
  const float* b1 = (const float*)d_in[9];
  const float* W2 = (const float*)d_in[10];
  const float* b2 = (const float*)d_in[11];
  float* h = (float*)d_out;

  char* ws = (char*)d_ws;
  __hip_bfloat16* wqkvT = (__hip_bfloat16*)ws; ws += (size_t)3072 * 1024 * 2;
  __hip_bfloat16* woutT = (__hip_bfloat16*)ws; ws += (size_t)1024 * 1024 * 2;
  __hip_bfloat16* w1T = (__hip_bfloat16*)ws;   ws += (size_t)4096 * 1024 * 2;
  __hip_bfloat16* w2T = (__hip_bfloat16*)ws;   ws += (size_t)1024 * 4096 * 2;
  __hip_bfloat16* ybuf = (__hip_bfloat16*)ws;  ws += (size_t)NTOK * 1024 * 2;
  __hip_bfloat16* qkvb = (__hip_bfloat16*)ws;  ws += (size_t)NTOK * 3072 * 2;
  __hip_bfloat16* vTb = (__hip_bfloat16*)ws;   ws += (size_t)32 * HD * SEQ * 2;
  __hip_bfloat16* obuf = (__hip_bfloat16*)ws;  ws += (size_t)NTOK * 1024 * 2;
  __hip_bfloat16* actb = (__hip_bfloat16*)ws;  ws += (size_t)NTOK * MLPD * 2;

  hipMemcpyAsync(h, x, (size_t)out_size * sizeof(float), hipMemcpyDeviceToDevice, stream);

  dim3 tb(32, 8);
  for (int l = 0; l < DEPTH; ++l) {
    transpose_cast4<<<12288, tb, 0, stream>>>(
        Wqkv + (size_t)l * 1024 * 3072, Wout + (size_t)l * 1024 * 1024,
        W1 + (size_t)l * 1024 * 4096, W2 + (size_t)l * 4096 * 1024,
        wqkvT, woutT, w1T, w2T);

    ln_kernel<<<NTOK, 256, 0, stream>>>(h, ln1g + l * 1024, ln1b + l * 1024, ybuf);
    // QKV: N=3072 -> 24 n-tiles, gpx=3; 768 blocks (V columns stream straight to vT)
    gemm128<3><<<768, 256, 0, stream>>>(ybuf, wqkvT, nullptr, qkvb, vTb, NTOK, 3072, 1024, 3);
    attn_kernel<<<dim3(SEQ / 64, 32), 256, 0, stream>>>(qkvb, vTb, obuf);
    // Oproj: N=1024 -> 16 n-tiles(64), gpx=2; 512 blocks, residual into h
    gemm64_res<<<512, 256, 0, stream>>>(obuf, woutT, bout + l * 1024, h, NTOK, 1024, 1024, 2);

    ln_kernel<<<NTOK, 256, 0, stream>>>(h, ln2g + l * 1024, ln2b + l * 1024, ybuf);
    // MLP1: N=4096 -> 32 n-tiles, gpx=4; 1024 blocks
    gemm128<1><<<1024, 256, 0, stream>>>(ybuf, w1T, b1 + l * 4096, actb, nullptr, NTOK, 4096, 1024, 4);
    // MLP2: N=1024 -> 16 n-tiles(64), gpx=2; 512 blocks, K=4096, residual into h
    gemm64_res<<<512, 256, 0, stream>>>(actb, w2T, b2 + l * 1024, h, NTOK, 1024, 4096, 2);
  }
}

// Round 3
// 1926.568 us; speedup vs baseline: 1.0974x; 1.0432x over previous
//
#include <hip/hip_runtime.h>
#include <hip/hip_bf16.h>
#include <math.h>

typedef __attribute__((__ext_vector_type__(8))) __bf16 bf16x8;
typedef __attribute__((__ext_vector_type__(4))) float f32x4;
typedef __attribute__((__ext_vector_type__(16))) float f32x16;

#define DIMQ 1024
#define SEQ 2048
#define NTOK 4096
#define HEADS 16
#define HD 64
#define MLPD 4096
#define DEPTH 6

__device__ __forceinline__ void gl_lds16(const __hip_bfloat16* g, __hip_bfloat16* l) {
  __builtin_amdgcn_global_load_lds((const __attribute__((address_space(1))) void*)(g),
                                   (__attribute__((address_space(3))) void*)(l), 16, 0, 0);
}

// packed f32x2 -> bf16x2 (RNE) in one instruction
__device__ __forceinline__ unsigned cvtpk_bf16(float lo, float hi) {
  unsigned r;
  asm("v_cvt_pk_bf16_f32 %0, %1, %2" : "=v"(r) : "v"(lo), "v"(hi));
  return r;
}

// ---------------- LayerNorm: one block per row (1024 cols) ----------------
__global__ __launch_bounds__(256) void ln_kernel(const float* __restrict__ h,
                                                 const float* __restrict__ g,
                                                 const float* __restrict__ bta,
                                                 __hip_bfloat16* __restrict__ y) {
  int row = blockIdx.x;
  int t = threadIdx.x;
  const float4* src = (const float4*)(h + (size_t)row * DIMQ);
  float4 xv = src[t];
  float s = xv.x + xv.y + xv.z + xv.w;
  float ss = xv.x * xv.x + xv.y * xv.y + xv.z * xv.z + xv.w * xv.w;
#pragma unroll
  for (int off = 32; off > 0; off >>= 1) {
    s += __shfl_xor(s, off);
    ss += __shfl_xor(ss, off);
  }
  __shared__ float red[8];
  int wid = t >> 6;
  if ((t & 63) == 0) { red[wid] = s; red[4 + wid] = ss; }
  __syncthreads();
  s = red[0] + red[1] + red[2] + red[3];
  ss = red[4] + red[5] + red[6] + red[7];
  float mean = s * (1.0f / DIMQ);
  float var = ss * (1.0f / DIMQ) - mean * mean;
  float rstd = rsqrtf(var + 1e-5f);
  float4 gv = ((const float4*)g)[t];
  float4 bv = ((const float4*)bta)[t];
  __hip_bfloat16* dst = y + (size_t)row * DIMQ + t * 4;
  dst[0] = __float2bfloat16((xv.x - mean) * rstd * gv.x + bv.x);
  dst[1] = __float2bfloat16((xv.y - mean) * rstd * gv.y + bv.y);
  dst[2] = __float2bfloat16((xv.z - mean) * rstd * gv.z + bv.z);
  dst[3] = __float2bfloat16((xv.w - mean) * rstd * gv.w + bv.w);
}

// ------- Batched weight transpose+cast: 4 matrices, fp32 [K][N] -> bf16 [N][K] -------
__global__ __launch_bounds__(256)
void transpose_cast4(const float* __restrict__ s0, const float* __restrict__ s1,
                     const float* __restrict__ s2, const float* __restrict__ s3,
                     __hip_bfloat16* __restrict__ d0, __hip_bfloat16* __restrict__ d1,
                     __hip_bfloat16* __restrict__ d2, __hip_bfloat16* __restrict__ d3) {
  __shared__ float t[32][33];
  int tb = blockIdx.x;
  const float* src;
  __hip_bfloat16* dst;
  int K, N;
  if (tb < 3072) { src = s0; dst = d0; K = 1024; N = 3072; }
  else if (tb < 4096) { tb -= 3072; src = s1; dst = d1; K = 1024; N = 1024; }
  else if (tb < 8192) { tb -= 4096; src = s2; dst = d2; K = 1024; N = 4096; }
  else { tb -= 8192; src = s3; dst = d3; K = 4096; N = 1024; }
  int ntx = N >> 5;
  int n0 = (tb % ntx) * 32, k0 = (tb / ntx) * 32;
  int tx = threadIdx.x, ty = threadIdx.y;
#pragma unroll
  for (int i = 0; i < 32; i += 8)
    t[ty + i][tx] = src[(size_t)(k0 + ty + i) * N + n0 + tx];
  __syncthreads();
#pragma unroll
  for (int i = 0; i < 32; i += 8)
    dst[(size_t)(n0 + ty + i) * K + k0 + tx] = __float2bfloat16(t[tx][ty + i]);
}

// ---------------- GEMM 128x128, BK=64, XOR-swizzled LDS, XCD-swizzled grid ----------------
template <int EPI>
__global__ __launch_bounds__(256)
void gemm128(const __hip_bfloat16* __restrict__ A, const __hip_bfloat16* __restrict__ BT,
             const float* __restrict__ bias, void* __restrict__ outp, void* __restrict__ outp2,
             int M, int N, int K, int gpx) {
  __shared__ __hip_bfloat16 As[128][64];
  __shared__ __hip_bfloat16 Bs[128][64];
  int bid = blockIdx.x;
  int xcd = bid & 7, jb = bid >> 3;
  int nt = xcd * gpx + (jb % gpx), mt = jb / gpx;
  int m0 = mt * 128, n0 = nt * 128;
  int tid = threadIdx.x;
  int lane = tid & 63, wid = tid >> 6;
  int l16 = lane & 15, quad = lane >> 4;
  int wm = (wid >> 1) * 64, wn = (wid & 1) * 64;
  int srsub = lane >> 3;
  int sg = (lane & 7) ^ srsub;
  f32x4 acc[4][4] = {};
  for (int kt = 0; kt < K; kt += 64) {
    __syncthreads();
#pragma unroll
    for (int s = 0; s < 4; ++s) {
      int r0 = (wid * 4 + s) * 8;
      gl_lds16(A + (size_t)(m0 + r0 + srsub) * K + kt + sg * 8, &As[r0][0]);
      gl_lds16(BT + (size_t)(n0 + r0 + srsub) * K + kt + sg * 8, &Bs[r0][0]);
    }
    __syncthreads();
#pragma unroll
    for (int ks = 0; ks < 2; ++ks) {
      bf16x8 af[4], bfr[4];
      int p = (ks * 4 + quad) ^ (l16 & 7);
#pragma unroll
      for (int i = 0; i < 4; ++i) af[i] = *(const bf16x8*)&As[wm + i * 16 + l16][p * 8];
#pragma unroll
      for (int j = 0; j < 4; ++j) bfr[j] = *(const bf16x8*)&Bs[wn + j * 16 + l16][p * 8];
#pragma unroll
      for (int i = 0; i < 4; ++i)
#pragma unroll
        for (int j = 0; j < 4; ++j)
          acc[i][j] = __builtin_amdgcn_mfma_f32_16x16x32_bf16(af[i], bfr[j], acc[i][j], 0, 0, 0);
    }
  }
#pragma unroll
  for (int j = 0; j < 4; ++j) {
    int col = n0 + wn + j * 16 + l16;
    if (EPI == 1) {
      float bv = bias[col];
#pragma unroll
      for (int i = 0; i < 4; ++i) {
#pragma unroll
        for (int r = 0; r < 4; ++r) {
          int row = m0 + wm + i * 16 + quad * 4 + r;
          float v = acc[i][j][r] + bv;
          v = 0.5f * v * (1.0f + erff(v * 0.70710678118654752f));
          ((__hip_bfloat16*)outp)[(size_t)row * N + col] = __float2bfloat16(v);
        }
      }
    } else {  // EPI 3
      int which = col >> 10;
      int head = (col >> 6) & 15;
      int d = col & 63;
      if (which < 2) {  // Q/K scatter to qkv [which][b,h][n][d]
#pragma unroll
        for (int i = 0; i < 4; ++i) {
#pragma unroll
          for (int r = 0; r < 4; ++r) {
            int row = m0 + wm + i * 16 + quad * 4 + r;
            size_t dst = (((size_t)which * 32 + (row >> 11) * 16 + head) * SEQ + (row & 2047)) * HD + d;
            ((__hip_bfloat16*)outp)[dst] = __float2bfloat16(acc[i][j][r]);
          }
        }
      } else {  // V: write vT [bh][d][n] directly, 4 consecutive n packed per store
        int bh2 = ((m0 >> 11) << 4) + head;
        unsigned short* vrow = (unsigned short*)outp2 + ((size_t)bh2 * HD + d) * SEQ;
        int nb = (m0 & 2047) + wm + quad * 4;
#pragma unroll
        for (int i = 0; i < 4; ++i) {
          uint2 pk;
          pk.x = cvtpk_bf16(acc[i][j][0], acc[i][j][1]);
          pk.y = cvtpk_bf16(acc[i][j][2], acc[i][j][3]);
          *(uint2*)(vrow + nb + i * 16) = pk;
        }
      }
    }
  }
}

// ---------------- GEMM 128x64, BK=64: fp32 residual h += acc + bias (no atomics) ----------
__global__ __launch_bounds__(256, 5)
void gemm64_res(const __hip_bfloat16* __restrict__ A, const __hip_bfloat16* __restrict__ BT,
                const float* __restrict__ bias, float* __restrict__ h,
                int M, int N, int K, int gpx) {
  __shared__ __hip_bfloat16 As[128][64];
  __shared__ __hip_bfloat16 Bs[64][64];
  int bid = blockIdx.x;
  int xcd = bid & 7, jb = bid >> 3;
  int nt = xcd * gpx + (jb % gpx), mt = jb / gpx;
  int m0 = mt * 128, n0 = nt * 64;
  int tid = threadIdx.x;
  int lane = tid & 63, wid = tid >> 6;
  int l16 = lane & 15, quad = lane >> 4;
  int wm = (wid >> 1) * 64, wn = (wid & 1) * 32;
  int srsub = lane >> 3;
  int sg = (lane & 7) ^ srsub;
  f32x4 acc[4][2] = {};
  for (int kt = 0; kt < K; kt += 64) {
    __syncthreads();
#pragma unroll
    for (int s = 0; s < 4; ++s) {
      int r0 = (wid * 4 + s) * 8;
      gl_lds16(A + (size_t)(m0 + r0 + srsub) * K + kt + sg * 8, &As[r0][0]);
    }
#pragma unroll
    for (int s = 0; s < 2; ++s) {
      int r0 = (wid * 2 + s) * 8;
      gl_lds16(BT + (size_t)(n0 + r0 + srsub) * K + kt + sg * 8, &Bs[r0][0]);
    }
    __syncthreads();
#pragma unroll
    for (int ks = 0; ks < 2; ++ks) {
      bf16x8 af[4], bfr[2];
      int p = (ks * 4 + quad) ^ (l16 & 7);
#pragma unroll
      for (int i = 0; i < 4; ++i) af[i] = *(const bf16x8*)&As[wm + i * 16 + l16][p * 8];
#pragma unroll
      for (int j = 0; j < 2; ++j) bfr[j] = *(const bf16x8*)&Bs[wn + j * 16 + l16][p * 8];
#pragma unroll
      for (int i = 0; i < 4; ++i)
#pragma unroll
        for (int j = 0; j < 2; ++j)
          acc[i][j] = __builtin_amdgcn_mfma_f32_16x16x32_bf16(af[i], bfr[j], acc[i][j], 0, 0, 0);
    }
  }
#pragma unroll
  for (int j = 0; j < 2; ++j) {
    int col = n0 + wn + j * 16 + l16;
    float bv = bias[col];
#pragma unroll
    for (int i = 0; i < 4; ++i) {
#pragma unroll
      for (int r = 0; r < 4; ++r) {
        int row = m0 + wm + i * 16 + quad * 4 + r;
        size_t idx = (size_t)row * N + col;
        h[idx] = h[idx] + acc[i][j][r] + bv;
      }
    }
  }
}

// ---------------- Flash attention: 32x32 MFMA, swapped QK^T, in-register softmax ----------
// Wave owns 32 q-rows. S^T = mfma(K,Q) puts q lane-local (col=lane&31); P stays in regs:
// exp -> cvt_pk pairs -> permlane32_swap builds the PV B-fragment. O^T = mfma(V^T, P).
// K/V double-buffered in LDS with counted vmcnt(4) (occupancy is grid-limited so dbuf free).
__global__ __launch_bounds__(256)
void attn_kernel(const __hip_bfloat16* __restrict__ qkvb, const __hip_bfloat16* __restrict__ vT,
                 __hip_bfloat16* __restrict__ o) {
  __shared__ __hip_bfloat16 Ks[2][64][64];
  __shared__ __hip_bfloat16 Vs[2][64][64];
  int bh = blockIdx.y;
  int b = bh >> 4, head = bh & 15;
  int tid = threadIdx.x;
  int wid = tid >> 6, lane = tid & 63;
  int l32 = lane & 31, hh = lane >> 5;
  int q0 = blockIdx.x * 128 + wid * 32;  // wave's 32-row q tile
  // Q fragments (B-operand): lane's q-row = q0+l32, d = k16*16 + hh*8 .. +7
  const __hip_bfloat16* qp = qkvb + ((size_t)bh * SEQ + q0 + l32) * HD + hh * 8;
  bf16x8 qf[4];
#pragma unroll
  for (int k16 = 0; k16 < 4; ++k16) qf[k16] = *(const bf16x8*)(qp + k16 * 16);

  f32x16 oaccT[2] = {};  // O^T accumulators for d-blocks 0,1
  float lsum = 0.0f;
  int srsub = lane >> 3;
  int sg = (lane & 7) ^ srsub;
  const __hip_bfloat16* kbase = qkvb + (size_t)(32 + bh) * SEQ * HD;
  const __hip_bfloat16* vbase = vT + (size_t)bh * HD * SEQ;
  const float c1 = 0.045084220027780106f;  // 1024^-0.5 * log2(e)

  int r0 = wid * 16, r1 = wid * 16 + 8;
#define STAGE_KV(bi, kb)                                                          \
  do {                                                                            \
    gl_lds16(kbase + (size_t)((kb) + r0 + srsub) * HD + sg * 8, &Ks[bi][r0][0]);  \
    gl_lds16(kbase + (size_t)((kb) + r1 + srsub) * HD + sg * 8, &Ks[bi][r1][0]);  \
    gl_lds16(vbase + (size_t)(r0 + srsub) * SEQ + (kb) + sg * 8, &Vs[bi][r0][0]); \
    gl_lds16(vbase + (size_t)(r1 + srsub) * SEQ + (kb) + sg * 8, &Vs[bi][r1][0]); \
  } while (0)

  STAGE_KV(0, 0);
  STAGE_KV(1, 64);

  for (int kb = 0; kb < SEQ; kb += 64) {
    int cur = (kb >> 6) & 1;
    asm volatile("s_waitcnt vmcnt(4)" ::: "memory");
    asm volatile("s_barrier" ::: "memory");
#pragma unroll
    for (int s = 0; s < 2; ++s) {  // two 32-row k subtiles
      // QK^T swapped: z = S^T[k=s*32+pattern][q=l32]
      f32x16 z = {};
      __builtin_amdgcn_s_setprio(1);
#pragma unroll
      for (int k16 = 0; k16 < 4; ++k16) {
        int krow = s * 32 + l32;
        int cc = k16 * 2 + hh;
        bf16x8 kf = *(const bf16x8*)&Ks[cur][krow][(cc ^ (krow & 7)) * 8];
        z = __builtin_amdgcn_mfma_f32_32x32x16_bf16(kf, qf[k16], z, 0, 0, 0);
      }
      __builtin_amdgcn_s_setprio(0);
      // exp + pack: reg pairs (2g,2g+1) are k-consecutive
      unsigned dw0, dw1, dw2, dw3, dw4, dw5, dw6, dw7;
      {
        float pa, pb;
        pa = exp2f(z[0] * c1);  pb = exp2f(z[1] * c1);  lsum += pa + pb; dw0 = cvtpk_bf16(pa, pb);
        pa = exp2f(z[2] * c1);  pb = exp2f(z[3] * c1);  lsum += pa + pb; dw1 = cvtpk_bf16(pa, pb);
        pa = exp2f(z[4] * c1);  pb = exp2f(z[5] * c1);  lsum += pa + pb; dw2 = cvtpk_bf16(pa, pb);
        pa = exp2f(z[6] * c1);  pb = exp2f(z[7] * c1);  lsum += pa + pb; dw3 = cvtpk_bf16(pa, pb);
        pa = exp2f(z[8] * c1);  pb = exp2f(z[9] * c1);  lsum += pa + pb; dw4 = cvtpk_bf16(pa, pb);
        pa = exp2f(z[10] * c1); pb = exp2f(z[11] * c1); lsum += pa + pb; dw5 = cvtpk_bf16(pa, pb);
        pa = exp2f(z[12] * c1); pb = exp2f(z[13] * c1); lsum += pa + pb; dw6 = cvtpk_bf16(pa, pb);
        pa = exp2f(z[14] * c1); pb = exp2f(z[15] * c1); lsum += pa + pb; dw7 = cvtpk_bf16(pa, pb);
      }
      // redistribute to PV B-frag layout: chunk0 (k=s*32+0..15) = {dw0,dw1,dw2,dw3},
      // chunk1 (k=s*32+16..31) = {dw4,dw5,dw6,dw7} after half-swaps
      asm volatile("v_permlane32_swap_b32 %0, %1" : "+v"(dw0), "+v"(dw2));
      asm volatile("v_permlane32_swap_b32 %0, %1" : "+v"(dw1), "+v"(dw3));
      asm volatile("v_permlane32_swap_b32 %0, %1" : "+v"(dw4), "+v"(dw6));
      asm volatile("v_permlane32_swap_b32 %0, %1" : "+v"(dw5), "+v"(dw7));
      union PU { unsigned u[4]; bf16x8 v; };
      PU p0u, p1u;
      p0u.u[0] = dw0; p0u.u[1] = dw1; p0u.u[2] = dw2; p0u.u[3] = dw3;
      p1u.u[0] = dw4; p1u.u[1] = dw5; p1u.u[2] = dw6; p1u.u[3] = dw7;
      // PV: O^T += V^T-frag x P-frag for the two 16-k chunks
      __builtin_amdgcn_s_setprio(1);
#pragma unroll
      for (int c = 0; c < 2; ++c) {
        bf16x8 pf = (c == 0) ? p0u.v : p1u.v;
        int cc = s * 4 + c * 2 + hh;
#pragma unroll
        for (int dblk = 0; dblk < 2; ++dblk) {
          int dr = dblk * 32 + l32;
          bf16x8 vf = *(const bf16x8*)&Vs[cur][dr][(cc ^ (dr & 7)) * 8];
          oaccT[dblk] = __builtin_amdgcn_mfma_f32_32x32x16_bf16(vf, pf, oaccT[dblk], 0, 0, 0);
        }
      }
      __builtin_amdgcn_s_setprio(0);
    }
    asm volatile("s_barrier" ::: "memory");
    int nk = kb + 128;
    if (nk >= SEQ) nk = 0;
    STAGE_KV(cur, nk);
  }
#undef STAGE_KV

  // finish row sums: combine the two lane-halves (same q = l32)
  lsum += __shfl_xor(lsum, 32);
  float inv = 1.0f / lsum;
  // write O: lane holds q = q0+l32, d = dblk*32 + (reg&3) + 8*(reg>>2) + 4*hh
  __hip_bfloat16* orow = o + ((size_t)b * SEQ + q0 + l32) * DIMQ + head * HD;
#pragma unroll
  for (int dblk = 0; dblk < 2; ++dblk) {
#pragma unroll
    for (int g2 = 0; g2 < 4; ++g2) {  // reg groups of 4 -> d = dblk*32 + g2*8 + 4*hh + 0..3
      uint2 pk;
      pk.x = cvtpk_bf16(oaccT[dblk][g2 * 4 + 0] * inv, oaccT[dblk][g2 * 4 + 1] * inv);
      pk.y = cvtpk_bf16(oaccT[dblk][g2 * 4 + 2] * inv, oaccT[dblk][g2 * 4 + 3] * inv);
      *(uint2*)(orow + dblk * 32 + g2 * 8 + 4 * hh) = pk;
    }
  }
}

// ---------------- Launcher ----------------
extern "C" void kernel_launch(void* const* d_in, const int* in_sizes, int n_in,
                              void* d_out, int out_size, void* d_ws, size_t ws_size,
                              hipStream_t stream) {
  const float* x = (const float*)d_in[0];
  const float* Wqkv = (const float*)d_in[1];
  const float* Wout = (const float*)d_in[2];
  const float* bout = (const float*)d_in[3];
  const float* ln1g = (const float*)d_in[4];
  const float* ln1b = (const float*)d_in[5];
  const float* ln2g = (const float*)d_in[6];
  const float* ln2b = (const float*)d_in[7];
  const float* W1 = (const float*)d_in[8];
  const float* b1 = (const float*)d_in[9];
  const float* W2 = (const float*)d_in[10];
  const float* b2 = (const float*)d_in[11];
  float* h = (float*)d_out;

  char* ws = (char*)d_ws;
  __hip_bfloat16* wqkvT = (__hip_bfloat16*)ws; ws += (size_t)3072 * 1024 * 2;
  __hip_bfloat16* woutT = (__hip_bfloat16*)ws; ws += (size_t)1024 * 1024 * 2;
  __hip_bfloat16* w1T = (__hip_bfloat16*)ws;   ws += (size_t)4096 * 1024 * 2;
  __hip_bfloat16* w2T = (__hip_bfloat16*)ws;   ws += (size_t)1024 * 4096 * 2;
  __hip_bfloat16* ybuf = (__hip_bfloat16*)ws;  ws += (size_t)NTOK * 1024 * 2;
  __hip_bfloat16* qkvb = (__hip_bfloat16*)ws;  ws += (size_t)NTOK * 3072 * 2;
  __hip_bfloat16* vTb = (__hip_bfloat16*)ws;   ws += (size_t)32 * HD * SEQ * 2;
  __hip_bfloat16* obuf = (__hip_bfloat16*)ws;  ws += (size_t)NTOK * 1024 * 2;
  __hip_bfloat16* actb = (__hip_bfloat16*)ws;  ws += (size_t)NTOK * MLPD * 2;

  hipMemcpyAsync(h, x, (size_t)out_size * sizeof(float), hipMemcpyDeviceToDevice, stream);

  dim3 tb(32, 8);
  for (int l = 0; l < DEPTH; ++l) {
    transpose_cast4<<<12288, tb, 0, stream>>>(
        Wqkv + (size_t)l * 1024 * 3072, Wout + (size_t)l * 1024 * 1024,
        W1 + (size_t)l * 1024 * 4096, W2 + (size_t)l * 4096 * 1024,
        wqkvT, woutT, w1T, w2T);

    ln_kernel<<<NTOK, 256, 0, stream>>>(h, ln1g + l * 1024, ln1b + l * 1024, ybuf);
    gemm128<3><<<768, 256, 0, stream>>>(ybuf, wqkvT, nullptr, qkvb, vTb, NTOK, 3072, 1024, 3);
    attn_kernel<<<dim3(SEQ / 128, 32), 256, 0, stream>>>(qkvb, vTb, obuf);
    gemm64_res<<<512, 256, 0, stream>>>(obuf, woutT, bout + l * 1024, h, NTOK, 1024, 1024, 2);

    ln_kernel<<<NTOK, 256, 0, stream>>>(h, ln2g + l * 1024, ln2b + l * 1024, ybuf);
    gemm128<1><<<1024, 256, 0, stream>>>(ybuf, w1T, b1 + l * 4096, actb, nullptr, NTOK, 4096, 1024, 4);
    gemm64_res<<<512, 256, 0, stream>>>(actb, w2T, b2 + l * 1024, h, NTOK, 1024, 4096, 2);
  }
}